// Round 21
// baseline (275.413 us; speedup 1.0000x reference)
//
#include <hip/hip_runtime.h>
#include <hip/hip_bf16.h>

typedef __attribute__((ext_vector_type(8))) short short8;
typedef __attribute__((ext_vector_type(4))) float f32x4;
typedef __attribute__((ext_vector_type(2))) float f32x2;

#define GLDS16(g, l)                                                        \
  __builtin_amdgcn_global_load_lds(                                         \
      (const __attribute__((address_space(1))) void*)(g),                   \
      (__attribute__((address_space(3))) void*)(l), 16, 0, 0)

__device__ __forceinline__ unsigned pkbf(float a, float b) {
  __hip_bfloat162 h = __float22bfloat162_rn(make_float2(a, b));
  return *reinterpret_cast<unsigned*>(&h);
}
__device__ __forceinline__ float bf2f(ushort u) {
  unsigned v = ((unsigned)u) << 16;
  return *reinterpret_cast<float*>(&v);
}

// ---------------- prep: ci = [Xc | cov]; wi tail = bf16(cov) ----------------
__global__ __launch_bounds__(256) void prep_ci(
    const float* __restrict__ X, const float* __restrict__ cov,
    float* __restrict__ ci, ushort* __restrict__ wi) {
  int i = blockIdx.x * 256 + threadIdx.x;
  if (i >= (512 * 4096) / 4) return;
  float4 x = ((const float4*)X)[i];
  float4 cv = ((const float4*)cov)[i];
  float4 xc, cm;
  xc.x = (x.x == x.x) ? x.x : 0.f; cm.x = (x.x == x.x) ? cv.x : 0.f;
  xc.y = (x.y == x.y) ? x.y : 0.f; cm.y = (x.y == x.y) ? cv.y : 0.f;
  xc.z = (x.z == x.z) ? x.z : 0.f; cm.z = (x.z == x.z) ? cv.z : 0.f;
  xc.w = (x.w == x.w) ? x.w : 0.f; cm.w = (x.w == x.w) ? cv.w : 0.f;
  int b = i >> 10;
  int m4 = (i & 1023) << 2;
  *(float4*)&ci[(long)b * 8192 + m4] = xc;
  *(float4*)&ci[(long)b * 8192 + 4096 + m4] = cm;
  // cov tail of wi (k in [65536,69632))
  int2 pc = make_int2(pkbf(cm.x, cm.y), pkbf(cm.z, cm.w));
  *(int2*)((char*)wi + (long)b * 139264 + 131072 + m4 * 2) = pc;
}

// ---- FUSED: gemm1 (blocks 0..511) | wm2cast (blocks 512..1535) ----
__global__ __launch_bounds__(256) void gemm1_cast(
    const float* __restrict__ ci, const float* __restrict__ W1,
    const float* __restrict__ Wm1, float* __restrict__ part,
    const float* __restrict__ Wm2, ushort* __restrict__ Wm2T) {
  __shared__ __align__(16) char usmem[33408];
  int t = threadIdx.x;
  if (blockIdx.x < 512) {
    // ---- gemm1: ci @ [W1|Wm1], split-K=32 -> partials ----
    float(*As)[128] = (float(*)[128])usmem;          // 4KB
    float(*Bs)[192] = (float(*)[192])(usmem + 4096); // 6KB (padded groups)
    int bid = blockIdx.x;
    int mt = bid & 3, nt = (bid >> 2) & 3, ks = bid >> 4;  // ks in [0,32)
    int row0 = mt * 128, n0 = nt * 128, k0 = ks * 256;
    const float* bsrc = (n0 < 256) ? (W1 + n0) : (Wm1 + (n0 - 256));
    int tx = t & 15, ty = t >> 4;
    int ar = t >> 1, ak = (t & 1) * 4;
    int bk = t >> 5, bn = (t & 31) * 4;
    int bcol = ((t & 31) >> 1) * 12 + ((t & 31) & 1) * 4;  // padded store col
    f32x2 acc[8][4];
#pragma unroll
    for (int i = 0; i < 8; i++)
#pragma unroll
      for (int j = 0; j < 4; j++) acc[i][j] = f32x2{0.f, 0.f};
    const float* aptr = ci + (long)(row0 + ar) * 8192 + k0 + ak;
    const float* bptr = bsrc + (long)(k0 + bk) * 256 + bn;
    float4 av = *(const float4*)aptr;
    float4 bv = *(const float4*)bptr;
    for (int kk0 = 8; kk0 <= 256; kk0 += 8) {
      __syncthreads();
      As[ak + 0][ar] = av.x; As[ak + 1][ar] = av.y;
      As[ak + 2][ar] = av.z; As[ak + 3][ar] = av.w;
      *(float4*)&Bs[bk][bcol] = bv;
      __syncthreads();
      if (kk0 < 256) {
        av = *(const float4*)(aptr + kk0);
        bv = *(const float4*)(bptr + (long)kk0 * 256);
      }
#pragma unroll
      for (int kk = 0; kk < 8; ++kk) {
        float4 a0 = *(float4*)&As[kk][ty * 8];
        float4 a1 = *(float4*)&As[kk][ty * 8 + 4];
        float4 b0 = *(float4*)&Bs[kk][tx * 12];
        float4 b1 = *(float4*)&Bs[kk][tx * 12 + 4];
        float aa[8] = {a0.x, a0.y, a0.z, a0.w, a1.x, a1.y, a1.z, a1.w};
        f32x2 bb[4] = {{b0.x, b0.y}, {b0.z, b0.w}, {b1.x, b1.y}, {b1.z, b1.w}};
#pragma unroll
        for (int i = 0; i < 8; i++) {
          f32x2 avv = {aa[i], aa[i]};
#pragma unroll
          for (int j = 0; j < 4; j++)
            acc[i][j] = __builtin_elementwise_fma(avv, bb[j], acc[i][j]);
        }
      }
    }
    float* P = part + ((long)ks * 512 + row0) * 512 + n0;
#pragma unroll
    for (int i = 0; i < 8; i++) {
      float4 v0 = {acc[i][0][0], acc[i][0][1], acc[i][1][0], acc[i][1][1]};
      float4 v1 = {acc[i][2][0], acc[i][2][1], acc[i][3][0], acc[i][3][1]};
      *(float4*)&P[(ty * 8 + i) * 512 + tx * 8] = v0;
      *(float4*)&P[(ty * 8 + i) * 512 + tx * 8 + 4] = v1;
    }
  } else {
    // ---- wm2cast: Wm2 [256][65536] fp32 -> Wm2T [65536][256] bf16 ----
    unsigned(*ld)[261] = (unsigned(*)[261])usmem;  // 33408B
    int ntile = blockIdx.x - 512;  // [0,1024)
    int kq = t >> 4, c4 = t & 15;
#pragma unroll
    for (int i = 0; i < 16; ++i) {
      int k = i * 16 + kq;
      float4 v = *(const float4*)(Wm2 + (long)k * 65536 + ntile * 64 + c4 * 4);
      ld[c4 * 2][k] = pkbf(v.x, v.y);
      ld[c4 * 2 + 1][k] = pkbf(v.z, v.w);
    }
    __syncthreads();
    int n = t & 63, kseg = t >> 6;
    const unsigned* row = ld[n >> 1];
    int hi = n & 1;
    ushort* out = Wm2T + ((long)ntile * 64 + n) * 256 + kseg * 64;
#pragma unroll
    for (int j = 0; j < 64; j += 8) {
      ushort tmp[8];
#pragma unroll
      for (int u = 0; u < 8; ++u) {
        unsigned w = row[kseg * 64 + j + u];
        tmp[u] = hi ? (ushort)(w >> 16) : (ushort)(w & 0xffff);
      }
      *(int4*)(out + j) = *(int4*)tmp;
    }
  }
}

// ---------------- block reduce helper ----------------
template <int NT>
__device__ __forceinline__ float block_sum(float v, float* red) {
#pragma unroll
  for (int o = 32; o > 0; o >>= 1) v += __shfl_down(v, o, 64);
  int w = threadIdx.x >> 6;
  if ((threadIdx.x & 63) == 0) red[w] = v;
  __syncthreads();
  float s = 0.f;
#pragma unroll
  for (int i = 0; i < NT / 64; ++i) s += red[i];
  __syncthreads();
  return s;
}

// --- reduce partials + LN + relu; FUSED est head (half==0 blocks) ---
// half==0 block holds the full h1 row in LDS -> run h2/est/argmin in wave 0
// (same-wave LDS ordering, no extra barriers). Kills est_head launch + h1.
__global__ __launch_bounds__(256) void ln_dual_est(
    const float* __restrict__ part,
    const float* __restrict__ b1, const float* __restrict__ g1, const float* __restrict__ be1,
    const float* __restrict__ bm1, const float* __restrict__ gm, const float* __restrict__ bem,
    ushort* __restrict__ lh,
    const float* __restrict__ W2, const float* __restrict__ b2,
    const float* __restrict__ g2, const float* __restrict__ be2,
    const float* __restrict__ W3, const float* __restrict__ b3,
    const float* __restrict__ cg, float* __restrict__ est, int* __restrict__ idxb) {
  __shared__ float red[4];
  __shared__ float row[256];
  __shared__ float h2s[64];
  int b = blockIdx.x >> 1, half = blockIdx.x & 1;
  int t = threadIdx.x;
  int n = half * 256 + t;
  float v = 0.f;
#pragma unroll
  for (int s = 0; s < 32; ++s) v += part[((long)s << 18) + b * 512 + n];
  v += half ? bm1[t] : b1[t];
  float mu = block_sum<256>(v, red) * (1.f / 256.f);
  float d = v - mu;
  float var = block_sum<256>(d * d, red) * (1.f / 256.f);
  float y = d / sqrtf(var + 1e-5f);
  y = y * (half ? gm[t] : g1[t]) + (half ? bem[t] : be1[t]);
  y = fmaxf(y, 0.f);
  if (half == 0) {
    row[t] = y;
    __syncthreads();
    if (t < 64) {
      float acc = b2[t];
      for (int k = 0; k < 256; ++k) acc += row[k] * W2[k * 64 + t];
      float s = acc;
#pragma unroll
      for (int o = 32; o > 0; o >>= 1) s += __shfl_xor(s, o, 64);
      float emu = s * (1.f / 64.f);
      float ed = acc - emu;
      float q = ed * ed;
#pragma unroll
      for (int o = 32; o > 0; o >>= 1) q += __shfl_xor(q, o, 64);
      float evar = q * (1.f / 64.f);
      float ey = ed / sqrtf(evar + 1e-5f) * g2[t] + be2[t];
      h2s[t] = fmaxf(ey, 0.f);  // same wave: LDS RAW ordered in program order
      if (t < 16) {
        float a = b3[t];
#pragma unroll
        for (int k = 0; k < 64; ++k) a += h2s[k] * W3[k * 16 + t];
        float e = 1.f / (1.f + expf(-a));
        est[b * 16 + t] = e;
        float best = 1e30f; int bi = 0;
        for (int j = 0; j < 50; ++j) {
          float dd = fabsf(cg[t * 50 + j] - e);
          if (dd < best) { best = dd; bi = j; }
        }
        idxb[b * 16 + t] = bi;
      }
    }
  } else {
    __hip_bfloat16 hb = __float2bfloat16(y);
    lh[b * 256 + t] = *reinterpret_cast<ushort*>(&hb);
  }
}

// --- MFMA GEMM M2: lh @ Wm2T -> sigmoid*dw -> mw + wi ---
// BM=64, BN=256, BK=64; group->XCD swizzle; bf16 Wm2T B-stage. LDS = 40960B
// EXACTLY (idxs moved to registers, preloaded before K-loop: per-wave-uniform
// scalar loads, hidden) -> 4 blocks/CU (was 3). Epilogue: two 32-row phases.
__global__ __launch_bounds__(512) void gemm_m2(
    const ushort* __restrict__ lh, const ushort* __restrict__ Wm2T,
    const float* __restrict__ bm2, const int* __restrict__ idxb,
    const float* __restrict__ dist, const float* __restrict__ ci,
    float* __restrict__ mw, ushort* __restrict__ wi) {
  __shared__ __align__(16) char smem[40960];
  char* Asl = smem;                   // 8KB: 64 rows x 128B, swizzled
  char* Bsl = smem + 8192;            // 32KB: 256 n x 128B, swizzled
  float* trb = (float*)smem;          // epilogue alias: [32][260] = 33280B

  int bid = blockIdx.x;                       // grid 2048
  int mt = (bid >> 3) & 7;                    // member within slice-group
  int nt = (bid & 7) + ((bid >> 6) << 3);     // group [0,256); members same XCD
  int b0 = mt * 64;
  long n0 = (long)nt * 256;
  int c = nt >> 4;
  int mbase = (nt & 15) * 256;
  int t = threadIdx.x;
  int lane = t & 63, wid = t >> 6;
  int wr = wid >> 2, wc = wid & 3;    // 2x4 waves, wave tile 32x64
  int rw = t >> 6;                    // epilogue row id (per-wave uniform)

  // preload the 8 idx values this thread needs (hidden under K-loop)
  int idxr[8];
#pragma unroll
  for (int p2 = 0; p2 < 2; ++p2)
#pragma unroll
    for (int jj = 0; jj < 4; ++jj)
      idxr[p2 * 4 + jj] = idxb[(b0 + p2 * 32 + rw + jj * 8) * 16 + c];

  f32x4 acc[2][4];
#pragma unroll
  for (int i = 0; i < 2; i++)
#pragma unroll
    for (int j = 0; j < 4; j++) acc[i][j] = f32x4{0.f, 0.f, 0.f, 0.f};

  int ar = t >> 3, ak = t & 7;        // A staging: row ar, 16B chunk ak
  int bn = t & 255, kh = t >> 8;      // B staging: n-row bn, 64B half kh

  for (int ks = 0; ks < 4; ++ks) {
    __syncthreads();  // prev MFMA done reading LDS
    {  // stage A: 64 rows x 64 k bf16, one int4 per thread
      int4 v = *(const int4*)(lh + (b0 + ar) * 256 + ks * 64 + ak * 8);
      int off = ar * 128 + ((ak * 16) ^ ((ar & 7) << 4));
      *(int4*)(Asl + off) = v;
    }
    {  // stage B: Wm2T row bn, k-slice [ks*64 + kh*32, +32) = 4 int4 contiguous
      const int4* bs = (const int4*)(Wm2T + (n0 + bn) * 256 + ks * 64 + kh * 32);
#pragma unroll
      for (int c4 = 0; c4 < 4; ++c4) {
        int4 v = bs[c4];
        int off = bn * 128 + ((kh * 64 + c4 * 16) ^ ((bn & 7) << 4));
        *(int4*)(Bsl + off) = v;
      }
    }
    asm volatile("s_waitcnt lgkmcnt(0)" ::: "memory");
    __builtin_amdgcn_s_barrier();
    __builtin_amdgcn_sched_barrier(0);
#pragma unroll
    for (int kk = 0; kk < 2; ++kk) {
      int kbyte = kk * 64 + (lane >> 4) * 16;
      short8 af[2], bfr[4];
#pragma unroll
      for (int rb = 0; rb < 2; ++rb) {
        int rr = wr * 32 + rb * 16 + (lane & 15);
        af[rb] = *(const short8*)(Asl + rr * 128 + (kbyte ^ ((rr & 7) << 4)));
      }
#pragma unroll
      for (int cb = 0; cb < 4; ++cb) {
        int nc = wc * 64 + cb * 16 + (lane & 15);
        bfr[cb] = *(const short8*)(Bsl + nc * 128 + (kbyte ^ ((nc & 7) << 4)));
      }
#pragma unroll
      for (int rb = 0; rb < 2; ++rb)
#pragma unroll
        for (int cb = 0; cb < 4; ++cb)
          acc[rb][cb] = __builtin_amdgcn_mfma_f32_16x16x32_bf16(af[rb], bfr[cb], acc[rb][cb], 0, 0, 0);
    }
  }

  // fold bias into acc (col depends only on cb)
#pragma unroll
  for (int cb = 0; cb < 4; ++cb) {
    float bv = bm2[n0 + wc * 64 + cb * 16 + (lane & 15)];
#pragma unroll
    for (int rb = 0; rb < 2; ++rb)
#pragma unroll
      for (int reg = 0; reg < 4; ++reg) acc[rb][cb][reg] += bv;
  }

  // ---- epilogue: 2 phases x 32 rows; loads issued at phase top ----
  int cg = (t & 63) * 4;  // float4 base col within 256
  const float* distC = dist + (long)c * 50 * 4096 + mbase;

#pragma unroll
  for (int p = 0; p < 2; ++p) {
    float4 fd[4], fx[4];
#pragma unroll
    for (int jj = 0; jj < 4; ++jj) {  // issue: fly over 2 barriers + scatter
      int g = p * 32 + rw + jj * 8;
      fd[jj] = *(const float4*)(distC + (long)idxr[p * 4 + jj] * 4096 + cg);
      fx[jj] = *(const float4*)(ci + (long)(b0 + g) * 8192 + mbase + cg);
    }
    __syncthreads();  // prev phase stream readers (or K-loop MFMA) done
    if (wr == p) {    // wr==p waves own block rows p*32..p*32+31
#pragma unroll
      for (int rb = 0; rb < 2; ++rb)
#pragma unroll
        for (int cb = 0; cb < 4; ++cb) {
          int tcol = wc * 64 + cb * 16 + (lane & 15);
          int trow0 = rb * 16 + (lane >> 4) * 4;
#pragma unroll
          for (int reg = 0; reg < 4; ++reg)
            trb[(trow0 + reg) * 260 + tcol] = acc[rb][cb][reg];
        }
    }
    __syncthreads();
#pragma unroll
    for (int jj = 0; jj < 4; ++jj) {
      int rq = rw + jj * 8;
      int g = p * 32 + rq;
      long brow = b0 + g;
      float4 tv = *(float4*)&trb[rq * 260 + cg];
      float4 dv = fd[jj], xv = fx[jj];
      float p0 = dv.x / (1.f + __expf(-tv.x));
      float p1 = dv.y / (1.f + __expf(-tv.y));
      float p2 = dv.z / (1.f + __expf(-tv.z));
      float p3 = dv.w / (1.f + __expf(-tv.w));
      f32x4 outv = {p0, p1, p2, p3};
      __builtin_nontemporal_store(outv, (f32x4*)(mw + brow * 65536 + n0 + cg));
      int2 wb = make_int2(pkbf(p0 * xv.x, p1 * xv.y), pkbf(p2 * xv.z, p3 * xv.w));
      *(int2*)(wi + brow * 69632 + n0 + cg) = wb;
    }
  }
}

// ---- MFMA GEMM F1: wi(bf16) @ Wf1 -> f1part[64] (bf16) ----
// BM=256 BN=128 BK=64, split-K=64 -> grid 512 = 2 resident blocks/CU.
// A via global_load_lds (dbuf, pre-swizzled source); B single-buffered.
__global__ __launch_bounds__(512) void gemm_f1(
    const ushort* __restrict__ wi, const float* __restrict__ Wf1,
    ushort* __restrict__ f1part) {
  __shared__ char Asl[2][32768];  // 256 rows x 128B (64 bf16), XOR-swizzled
  __shared__ char Bsl[16384];     // 128 n    x 128B, XOR-swizzled (single)
  int bid = blockIdx.x;
  int L = (bid & 7) * 64 + (bid >> 3);  // XCD swizzle: same-kb tiles colocate
  int kb = L >> 3;                       // [0,64)
  int tile = L & 7;
  int mt = tile >> 2, nt = tile & 3;
  int b0 = mt * 256, n0 = nt * 128;
  int kc0 = kb * 1088;
  int t = threadIdx.x;
  int lane = t & 63, wid = t >> 6;
  int wr = wid >> 1, wc = wid & 1;  // 4x2 waves, wave tile 64x64

  f32x4 acc[4][4];
#pragma unroll
  for (int i = 0; i < 4; i++)
#pragma unroll
    for (int j = 0; j < 4; j++) acc[i][j] = f32x4{0.f, 0.f, 0.f, 0.f};

  int nn = t & 127, kg = (t >> 7) & 3;  // B loader roles
  float bvv[16];

  const char* wib = (const char*)wi;
  long arowbase = (long)(b0 + wid * 32 + (lane >> 3)) * 139264 +
                  (((lane & 7) ^ (lane >> 3)) << 4);

  auto STAGE_A = [&](int bi, int s) {
    const char* g0 = wib + arowbase + (long)(kc0 + s * 64) * 2;
    char* l0 = &Asl[bi][wid * 4096];
#pragma unroll
    for (int i = 0; i < 4; ++i)
      GLDS16(g0 + (long)i * 8 * 139264, l0 + i * 1024);
  };
  auto LOAD_B = [&](int s) {
    const float* bs = Wf1 + (long)(kc0 + s * 64 + kg * 16) * 512 + n0 + nn;
#pragma unroll
    for (int j = 0; j < 16; ++j) bvv[j] = bs[(long)j * 512];
  };
  auto WRITE_B = [&]() {
    unsigned p[8];
#pragma unroll
    for (int j = 0; j < 8; ++j) p[j] = pkbf(bvv[2 * j], bvv[2 * j + 1]);
    int o0 = nn * 128 + ((kg * 32) ^ ((nn & 7) << 4));
    int o1 = nn * 128 + ((kg * 32 + 16) ^ ((nn & 7) << 4));
    *(int4*)(Bsl + o0) = make_int4(p[0], p[1], p[2], p[3]);
    *(int4*)(Bsl + o1) = make_int4(p[4], p[5], p[6], p[7]);
  };

  STAGE_A(0, 0);
  LOAD_B(0);
  int cur = 0;
  for (int s = 0; s < 17; ++s) {
    __syncthreads();  // drains vmcnt: A(s) in LDS, bvv(s) in regs; Bsl free
    WRITE_B();
    if (s < 16) {
      STAGE_A(cur ^ 1, s + 1);  // issue next-step loads: in flight over MFMA
      LOAD_B(s + 1);
    }
    asm volatile("s_waitcnt lgkmcnt(0)" ::: "memory");  // my ds_writes done
    __builtin_amdgcn_s_barrier();                       // B visible; vmcnt live
    __builtin_amdgcn_sched_barrier(0);
    const char* Ab = &Asl[cur][0];
#pragma unroll
    for (int kk = 0; kk < 2; ++kk) {
      int kbyte = kk * 64 + (lane >> 4) * 16;
      short8 af[4], bfr[4];
#pragma unroll
      for (int rb = 0; rb < 4; ++rb) {
        int rr = wr * 64 + rb * 16 + (lane & 15);
        af[rb] = *(const short8*)(Ab + rr * 128 + (kbyte ^ ((rr & 7) << 4)));
      }
#pragma unroll
      for (int cb = 0; cb < 4; ++cb) {
        int nc = wc * 64 + cb * 16 + (lane & 15);
        bfr[cb] = *(const short8*)(Bsl + nc * 128 + (kbyte ^ ((nc & 7) << 4)));
      }
#pragma unroll
      for (int rb = 0; rb < 4; ++rb)
#pragma unroll
        for (int cb = 0; cb < 4; ++cb)
          acc[rb][cb] = __builtin_amdgcn_mfma_f32_16x16x32_bf16(af[rb], bfr[cb], acc[rb][cb], 0, 0, 0);
    }
    cur ^= 1;
  }
  ushort* P = f1part + (long)kb * 262144;
#pragma unroll
  for (int rb = 0; rb < 4; ++rb)
#pragma unroll
    for (int cb = 0; cb < 4; ++cb) {
      int nl = n0 + wc * 64 + cb * 16 + (lane & 15);
#pragma unroll
      for (int reg = 0; reg < 4; ++reg) {
        int bl = b0 + wr * 64 + rb * 16 + (lane >> 4) * 4 + reg;
        __hip_bfloat16 hb = __float2bfloat16(acc[rb][cb][reg]);
        P[bl * 512 + nl] = *reinterpret_cast<ushort*>(&hb);
      }
    }
}

// ------------- reduce f1part (64 x bf16) + LN + relu -------------
__global__ __launch_bounds__(512) void ln_f1(
    const ushort* __restrict__ f1part, const float* __restrict__ bf1,
    const float* __restrict__ gf1, const float* __restrict__ bef1,
    float* __restrict__ f1ln) {
  __shared__ float red[8];
  int b = blockIdx.x, t = threadIdx.x;
  float v = bf1[t];
#pragma unroll
  for (int s = 0; s < 64; ++s) v += bf2f(f1part[(long)s * 262144 + b * 512 + t]);
  float mu = block_sum<512>(v, red) * (1.f / 512.f);
  float d = v - mu;
  float var = block_sum<512>(d * d, red) * (1.f / 512.f);
  float y = d / sqrtf(var + 1e-5f) * gf1[t] + bef1[t];
  f1ln[b * 512 + t] = fmaxf(y, 0.f);
}

// ------------- f2 = relu(LN(f1ln @ Wf2 + bf2)) -------------
__global__ __launch_bounds__(256) void f2_head(
    const float* __restrict__ f1ln, const float* __restrict__ Wf2,
    const float* __restrict__ bf2, const float* __restrict__ gf2,
    const float* __restrict__ bef2, float* __restrict__ f2) {
  __shared__ float row[512];
  __shared__ float red[4];
  int b = blockIdx.x, t = threadIdx.x;
  row[t] = f1ln[b * 512 + t];
  row[t + 256] = f1ln[b * 512 + 256 + t];
  __syncthreads();
  float acc = bf2[t];
  for (int k = 0; k < 512; ++k) acc += row[k] * Wf2[k * 256 + t];
  float mu = block_sum<256>(acc, red) * (1.f / 256.f);
  float d = acc - mu;
  float var = block_sum<256>(d * d, red) * (1.f / 256.f);
  float y = d / sqrtf(var + 1e-5f) * gf2[t] + bef2[t];
  f2[b * 256 + t] = fmaxf(y, 0.f);
}

// ------------- logits -> softmax -> final -------------
__global__ __launch_bounds__(64) void final_head(
    const float* __restrict__ f2, const float* __restrict__ Wo,
    const float* __restrict__ bo, const float* __restrict__ est,
    float* __restrict__ fin) {
  __shared__ float row[256];
  int b = blockIdx.x, t = threadIdx.x;
#pragma unroll
  for (int i = 0; i < 4; ++i) row[t + i * 64] = f2[b * 256 + t + i * 64];
  __syncthreads();
  float lg = -1e30f;
  if (t < 16) {
    lg = bo[t];
    for (int k = 0; k < 256; ++k) lg += row[k] * Wo[k * 16 + t];
  }
  float m = lg;
#pragma unroll
  for (int o = 8; o > 0; o >>= 1) m = fmaxf(m, __shfl_xor(m, o, 64));
  float e = (t < 16) ? expf(lg - m) : 0.f;
  float ssum = e;
#pragma unroll
  for (int o = 8; o > 0; o >>= 1) ssum += __shfl_xor(ssum, o, 64);
  if (t < 16) fin[b * 16 + t] = 0.5f * (e / ssum + est[b * 16 + t]);
}

extern "C" void kernel_launch(void* const* d_in, const int* in_sizes, int n_in,
                              void* d_out, int out_size, void* d_ws, size_t ws_size,
                              hipStream_t stream) {
  const float* X = (const float*)d_in[0];
  const float* coverage = (const float*)d_in[1];
  const float* conc_grid = (const float*)d_in[2];
  const float* dist_table = (const float*)d_in[3];
  const float* W1 = (const float*)d_in[4];
  const float* b1 = (const float*)d_in[5];
  const float* g1 = (const float*)d_in[6];
  const float* be1 = (const float*)d_in[7];
  const float* W2 = (const float*)d_in[8];
  const float* b2 = (const float*)d_in[9];
  const float* g2 = (const float*)d_in[10];
  const float* be2 = (const float*)d_in[11];
  const float* W3 = (const float*)d_in[12];
  const float* b3 = (const float*)d_in[13];
  const float* Wm1 = (const float*)d_in[14];
  const float* bm1 = (const float*)d_in[15];
  const float* gm = (const float*)d_in[16];
  const float* bem = (const float*)d_in[17];
  const float* Wm2 = (const float*)d_in[18];
  const float* bm2 = (const float*)d_in[19];
  const float* Wf1 = (const float*)d_in[20];
  const float* bf1 = (const float*)d_in[21];
  const float* gf1 = (const float*)d_in[22];
  const float* bef1 = (const float*)d_in[23];
  const float* Wf2 = (const float*)d_in[24];
  const float* bf2 = (const float*)d_in[25];
  const float* gf2 = (const float*)d_in[26];
  const float* bef2 = (const float*)d_in[27];
  const float* Wo = (const float*)d_in[28];
  const float* bo = (const float*)d_in[29];

  float* out_final = (float*)d_out;
  float* out_est = out_final + 8192;
  float* out_mw = out_final + 16384;

  char* ws = (char*)d_ws;
  float* ci = (float*)(ws);                       // 16.78 MB
  float* part = (float*)(ws + 16777216);          // 33.5 MB (gemm1 partials)
  ushort* f1part = (ushort*)(ws + 16777216);      // 33.5 MB (aliases part; after gemm_m2)
  ushort* lh = (ushort*)(ws + 50855936);          // 256 KB bf16
  int* idxb = (int*)(ws + 51118080);              // 32 KB
  float* f1ln = (float*)(ws + 51150848);          // 1 MB
  float* f2 = (float*)(ws + 52199424);            // 512 KB
  ushort* wi = (ushort*)(ws + 52723712);          // 71.3 MB bf16 [512][69632]
  ushort* Wm2T = (ushort*)(ws + 124780544);       // 33.5 MB (separate: coexists with part)

  prep_ci<<<2048, 256, 0, stream>>>(X, coverage, ci, wi);
  gemm1_cast<<<1536, 256, 0, stream>>>(ci, W1, Wm1, part, Wm2, Wm2T);
  ln_dual_est<<<1024, 256, 0, stream>>>(part, b1, g1, be1, bm1, gm, bem, lh,
                                        W2, b2, g2, be2, W3, b3, conc_grid,
                                        out_est, idxb);
  gemm_m2<<<2048, 512, 0, stream>>>(lh, Wm2T, bm2, idxb, dist_table, ci, out_mw, wi);
  gemm_f1<<<512, 512, 0, stream>>>(wi, Wf1, f1part);
  ln_f1<<<512, 512, 0, stream>>>(f1part, bf1, gf1, bef1, f1ln);
  f2_head<<<512, 256, 0, stream>>>(f1ln, Wf2, bf2, gf2, bef2, f2);
  final_head<<<512, 64, 0, stream>>>(f2, Wo, bo, out_est, out_final);
}

// Round 22
// 270.854 us; speedup vs baseline: 1.0168x; 1.0168x over previous
//
#include <hip/hip_runtime.h>
#include <hip/hip_bf16.h>

typedef __attribute__((ext_vector_type(8))) short short8;
typedef __attribute__((ext_vector_type(4))) float f32x4;

#define GLDS16(g, l)                                                        \
  __builtin_amdgcn_global_load_lds(                                         \
      (const __attribute__((address_space(1))) void*)(g),                   \
      (__attribute__((address_space(3))) void*)(l), 16, 0, 0)

__device__ __forceinline__ unsigned pkbf(float a, float b) {
  __hip_bfloat162 h = __float22bfloat162_rn(make_float2(a, b));
  return *reinterpret_cast<unsigned*>(&h);
}
__device__ __forceinline__ float bf2f(ushort u) {
  unsigned v = ((unsigned)u) << 16;
  return *reinterpret_cast<float*>(&v);
}

// ---------------- prep: ci = [Xc | cov]; wi tail = bf16(cov) ----------------
__global__ __launch_bounds__(256) void prep_ci(
    const float* __restrict__ X, const float* __restrict__ cov,
    float* __restrict__ ci, ushort* __restrict__ wi) {
  int i = blockIdx.x * 256 + threadIdx.x;
  if (i >= (512 * 4096) / 4) return;
  float4 x = ((const float4*)X)[i];
  float4 cv = ((const float4*)cov)[i];
  float4 xc, cm;
  xc.x = (x.x == x.x) ? x.x : 0.f; cm.x = (x.x == x.x) ? cv.x : 0.f;
  xc.y = (x.y == x.y) ? x.y : 0.f; cm.y = (x.y == x.y) ? cv.y : 0.f;
  xc.z = (x.z == x.z) ? x.z : 0.f; cm.z = (x.z == x.z) ? cv.z : 0.f;
  xc.w = (x.w == x.w) ? x.w : 0.f; cm.w = (x.w == x.w) ? cv.w : 0.f;
  int b = i >> 10;
  int m4 = (i & 1023) << 2;
  *(float4*)&ci[(long)b * 8192 + m4] = xc;
  *(float4*)&ci[(long)b * 8192 + 4096 + m4] = cm;
  // cov tail of wi (k in [65536,69632))
  int2 pc = make_int2(pkbf(cm.x, cm.y), pkbf(cm.z, cm.w));
  *(int2*)((char*)wi + (long)b * 139264 + 131072 + m4 * 2) = pc;
}

// ---- FUSED: gemm1 (blocks 0..511) | wm2cast (blocks 512..1535) ----
// Independent inputs/outputs; gemm1 is VALU/LDS-bound, wm2cast is HBM-bound
// -> block-level co-scheduling overlaps them (serial launches just add).
__global__ __launch_bounds__(256) void gemm1_cast(
    const float* __restrict__ ci, const float* __restrict__ W1,
    const float* __restrict__ Wm1, float* __restrict__ part,
    const float* __restrict__ Wm2, ushort* __restrict__ Wm2T) {
  __shared__ __align__(16) char usmem[33408];
  int t = threadIdx.x;
  if (blockIdx.x < 512) {
    // ---- gemm1: ci @ [W1|Wm1], split-K=32 -> partials ----
    float(*As)[128] = (float(*)[128])usmem;          // 4KB
    float(*Bs)[128] = (float(*)[128])(usmem + 4096); // 4KB
    int bid = blockIdx.x;
    int mt = bid & 3, nt = (bid >> 2) & 3, ks = bid >> 4;  // ks in [0,32)
    int row0 = mt * 128, n0 = nt * 128, k0 = ks * 256;
    const float* bsrc = (n0 < 256) ? (W1 + n0) : (Wm1 + (n0 - 256));
    int tx = t & 15, ty = t >> 4;
    int ar = t >> 1, ak = (t & 1) * 4;
    int bk = t >> 5, bn = (t & 31) * 4;
    float acc[8][8] = {};
    const float* aptr = ci + (long)(row0 + ar) * 8192 + k0 + ak;
    const float* bptr = bsrc + (long)(k0 + bk) * 256 + bn;
    float4 av = *(const float4*)aptr;
    float4 bv = *(const float4*)bptr;
    for (int kk0 = 8; kk0 <= 256; kk0 += 8) {
      __syncthreads();
      As[ak + 0][ar] = av.x; As[ak + 1][ar] = av.y;
      As[ak + 2][ar] = av.z; As[ak + 3][ar] = av.w;
      *(float4*)&Bs[bk][bn] = bv;
      __syncthreads();
      if (kk0 < 256) {
        av = *(const float4*)(aptr + kk0);
        bv = *(const float4*)(bptr + (long)kk0 * 256);
      }
#pragma unroll
      for (int kk = 0; kk < 8; ++kk) {
        float4 a0 = *(float4*)&As[kk][ty * 8];
        float4 a1 = *(float4*)&As[kk][ty * 8 + 4];
        float4 b0 = *(float4*)&Bs[kk][tx * 8];
        float4 b1 = *(float4*)&Bs[kk][tx * 8 + 4];
        float aa[8] = {a0.x, a0.y, a0.z, a0.w, a1.x, a1.y, a1.z, a1.w};
        float bb[8] = {b0.x, b0.y, b0.z, b0.w, b1.x, b1.y, b1.z, b1.w};
#pragma unroll
        for (int i = 0; i < 8; i++)
#pragma unroll
          for (int j = 0; j < 8; j++) acc[i][j] += aa[i] * bb[j];
      }
    }
    float* P = part + ((long)ks * 512 + row0) * 512 + n0;
#pragma unroll
    for (int i = 0; i < 8; i++)
#pragma unroll
      for (int j = 0; j < 8; j += 4) {
        float4 vv = {acc[i][j], acc[i][j + 1], acc[i][j + 2], acc[i][j + 3]};
        *(float4*)&P[(ty * 8 + i) * 512 + tx * 8 + j] = vv;
      }
  } else {
    // ---- wm2cast: Wm2 [256][65536] fp32 -> Wm2T [65536][256] bf16 ----
    // LDS [n/2][k] stride 261 (coprime 32): conflict-free write-phase reads.
    unsigned(*ld)[261] = (unsigned(*)[261])usmem;  // 33408B
    int ntile = blockIdx.x - 512;  // [0,1024)
    int kq = t >> 4, c4 = t & 15;
#pragma unroll
    for (int i = 0; i < 16; ++i) {
      int k = i * 16 + kq;
      float4 v = *(const float4*)(Wm2 + (long)k * 65536 + ntile * 64 + c4 * 4);
      ld[c4 * 2][k] = pkbf(v.x, v.y);
      ld[c4 * 2 + 1][k] = pkbf(v.z, v.w);
    }
    __syncthreads();
    int n = t & 63, kseg = t >> 6;
    const unsigned* row = ld[n >> 1];
    int hi = n & 1;
    ushort* out = Wm2T + ((long)ntile * 64 + n) * 256 + kseg * 64;
#pragma unroll
    for (int j = 0; j < 64; j += 8) {
      ushort tmp[8];
#pragma unroll
      for (int u = 0; u < 8; ++u) {
        unsigned w = row[kseg * 64 + j + u];
        tmp[u] = hi ? (ushort)(w >> 16) : (ushort)(w & 0xffff);
      }
      *(int4*)(out + j) = *(int4*)tmp;
    }
  }
}

// ---------------- block reduce helper ----------------
template <int NT>
__device__ __forceinline__ float block_sum(float v, float* red) {
#pragma unroll
  for (int o = 32; o > 0; o >>= 1) v += __shfl_down(v, o, 64);
  int w = threadIdx.x >> 6;
  if ((threadIdx.x & 63) == 0) red[w] = v;
  __syncthreads();
  float s = 0.f;
#pragma unroll
  for (int i = 0; i < NT / 64; ++i) s += red[i];
  __syncthreads();
  return s;
}

// ------------- reduce partials + LN + relu; h1 fp32, lh bf16 -------------
__global__ __launch_bounds__(256) void ln_dual(
    const float* __restrict__ part,
    const float* __restrict__ b1, const float* __restrict__ g1, const float* __restrict__ be1,
    const float* __restrict__ bm1, const float* __restrict__ gm, const float* __restrict__ bem,
    float* __restrict__ h1, ushort* __restrict__ lh) {
  __shared__ float red[4];
  int b = blockIdx.x >> 1, half = blockIdx.x & 1;
  int t = threadIdx.x;
  int n = half * 256 + t;
  float v = 0.f;
#pragma unroll
  for (int s = 0; s < 32; ++s) v += part[((long)s << 18) + b * 512 + n];
  v += half ? bm1[t] : b1[t];
  float mu = block_sum<256>(v, red) * (1.f / 256.f);
  float d = v - mu;
  float var = block_sum<256>(d * d, red) * (1.f / 256.f);
  float y = d / sqrtf(var + 1e-5f);
  y = y * (half ? gm[t] : g1[t]) + (half ? bem[t] : be1[t]);
  y = fmaxf(y, 0.f);
  if (half == 0) {
    h1[b * 256 + t] = y;
  } else {
    __hip_bfloat16 hb = __float2bfloat16(y);
    lh[b * 256 + t] = *reinterpret_cast<ushort*>(&hb);
  }
}

// ------------- est head: h1->h2->est->argmin idx -------------
__global__ __launch_bounds__(64) void est_head(
    const float* __restrict__ h1, const float* __restrict__ W2, const float* __restrict__ b2,
    const float* __restrict__ g2, const float* __restrict__ be2,
    const float* __restrict__ W3, const float* __restrict__ b3,
    const float* __restrict__ cg, float* __restrict__ est, int* __restrict__ idxb) {
  __shared__ float row[256];
  __shared__ float h2s[64];
  int b = blockIdx.x, t = threadIdx.x;
#pragma unroll
  for (int i = 0; i < 4; ++i) row[t + i * 64] = h1[b * 256 + t + i * 64];
  __syncthreads();
  float acc = b2[t];
  for (int k = 0; k < 256; ++k) acc += row[k] * W2[k * 64 + t];
  float s = acc;
#pragma unroll
  for (int o = 32; o > 0; o >>= 1) s += __shfl_xor(s, o, 64);
  float mu = s * (1.f / 64.f);
  float d = acc - mu;
  float q = d * d;
#pragma unroll
  for (int o = 32; o > 0; o >>= 1) q += __shfl_xor(q, o, 64);
  float var = q * (1.f / 64.f);
  float y = d / sqrtf(var + 1e-5f) * g2[t] + be2[t];
  h2s[t] = fmaxf(y, 0.f);
  __syncthreads();
  if (t < 16) {
    float a = b3[t];
#pragma unroll
    for (int k = 0; k < 64; ++k) a += h2s[k] * W3[k * 16 + t];
    float e = 1.f / (1.f + expf(-a));
    est[b * 16 + t] = e;
    float best = 1e30f; int bi = 0;
    for (int j = 0; j < 50; ++j) {
      float dd = fabsf(cg[t * 50 + j] - e);
      if (dd < best) { best = dd; bi = j; }
    }
    idxb[b * 16 + t] = bi;
  }
}

// --- MFMA GEMM M2: lh @ Wm2T -> sigmoid*dw -> mw + wi ---
// BM=64, BN=256, BK=64, 3 blocks/CU; group->XCD swizzle; bf16 Wm2T B-stage.
// Epilogue: two 32-row phases.
__global__ __launch_bounds__(512) void gemm_m2(
    const ushort* __restrict__ lh, const ushort* __restrict__ Wm2T,
    const float* __restrict__ bm2, const int* __restrict__ idxb,
    const float* __restrict__ dist, const float* __restrict__ ci,
    float* __restrict__ mw, ushort* __restrict__ wi) {
  __shared__ __align__(16) char smem[41216];
  char* Asl = smem;                   // 8KB: 64 rows x 128B, swizzled
  char* Bsl = smem + 8192;            // 32KB: 256 n x 128B, swizzled
  float* trb = (float*)smem;          // epilogue alias: [32][260] = 33280B
  int* idxs = (int*)(smem + 40960);   // 256B, persists

  int bid = blockIdx.x;                       // grid 2048
  int mt = (bid >> 3) & 7;                    // member within slice-group
  int nt = (bid & 7) + ((bid >> 6) << 3);     // group [0,256); members same XCD
  int b0 = mt * 64;
  long n0 = (long)nt * 256;
  int c = nt >> 4;
  int mbase = (nt & 15) * 256;
  int t = threadIdx.x;
  int lane = t & 63, wid = t >> 6;
  int wr = wid >> 2, wc = wid & 3;    // 2x4 waves, wave tile 32x64

  if (t < 64) idxs[t] = idxb[(b0 + t) * 16 + c];

  f32x4 acc[2][4];
#pragma unroll
  for (int i = 0; i < 2; i++)
#pragma unroll
    for (int j = 0; j < 4; j++) acc[i][j] = f32x4{0.f, 0.f, 0.f, 0.f};

  int ar = t >> 3, ak = t & 7;        // A staging: row ar, 16B chunk ak
  int bn = t & 255, kh = t >> 8;      // B staging: n-row bn, 64B half kh

  for (int ks = 0; ks < 4; ++ks) {
    __syncthreads();  // prev MFMA done reading LDS
    {  // stage A: 64 rows x 64 k bf16, one int4 per thread
      int4 v = *(const int4*)(lh + (b0 + ar) * 256 + ks * 64 + ak * 8);
      int off = ar * 128 + ((ak * 16) ^ ((ar & 7) << 4));
      *(int4*)(Asl + off) = v;
    }
    {  // stage B: Wm2T row bn, k-slice [ks*64 + kh*32, +32) = 4 int4 contiguous
      const int4* bs = (const int4*)(Wm2T + (n0 + bn) * 256 + ks * 64 + kh * 32);
#pragma unroll
      for (int c4 = 0; c4 < 4; ++c4) {
        int4 v = bs[c4];
        int off = bn * 128 + ((kh * 64 + c4 * 16) ^ ((bn & 7) << 4));
        *(int4*)(Bsl + off) = v;
      }
    }
    asm volatile("s_waitcnt lgkmcnt(0)" ::: "memory");
    __builtin_amdgcn_s_barrier();
    __builtin_amdgcn_sched_barrier(0);
#pragma unroll
    for (int kk = 0; kk < 2; ++kk) {
      int kbyte = kk * 64 + (lane >> 4) * 16;
      short8 af[2], bfr[4];
#pragma unroll
      for (int rb = 0; rb < 2; ++rb) {
        int rr = wr * 32 + rb * 16 + (lane & 15);
        af[rb] = *(const short8*)(Asl + rr * 128 + (kbyte ^ ((rr & 7) << 4)));
      }
#pragma unroll
      for (int cb = 0; cb < 4; ++cb) {
        int nc = wc * 64 + cb * 16 + (lane & 15);
        bfr[cb] = *(const short8*)(Bsl + nc * 128 + (kbyte ^ ((nc & 7) << 4)));
      }
#pragma unroll
      for (int rb = 0; rb < 2; ++rb)
#pragma unroll
        for (int cb = 0; cb < 4; ++cb)
          acc[rb][cb] = __builtin_amdgcn_mfma_f32_16x16x32_bf16(af[rb], bfr[cb], acc[rb][cb], 0, 0, 0);
    }
  }

  // fold bias into acc (col depends only on cb)
#pragma unroll
  for (int cb = 0; cb < 4; ++cb) {
    float bv = bm2[n0 + wc * 64 + cb * 16 + (lane & 15)];
#pragma unroll
    for (int rb = 0; rb < 2; ++rb)
#pragma unroll
      for (int reg = 0; reg < 4; ++reg) acc[rb][cb][reg] += bv;
  }

  // ---- epilogue: 2 phases x 32 rows; loads issued at phase top ----
  int cg = (t & 63) * 4;  // float4 base col within 256
  int rw = t >> 6;        // 0..7; rows rw+{0,8,16,24} of the 32-row phase
  const float* distC = dist + (long)c * 50 * 4096 + mbase;

#pragma unroll
  for (int p = 0; p < 2; ++p) {
    float4 fd[4], fx[4];
#pragma unroll
    for (int jj = 0; jj < 4; ++jj) {  // issue: fly over 2 barriers + scatter
      int g = p * 32 + rw + jj * 8;
      fd[jj] = *(const float4*)(distC + (long)idxs[g] * 4096 + cg);
      fx[jj] = *(const float4*)(ci + (long)(b0 + g) * 8192 + mbase + cg);
    }
    __syncthreads();  // prev phase stream readers (or K-loop MFMA) done
    if (wr == p) {    // wr==p waves own block rows p*32..p*32+31
#pragma unroll
      for (int rb = 0; rb < 2; ++rb)
#pragma unroll
        for (int cb = 0; cb < 4; ++cb) {
          int tcol = wc * 64 + cb * 16 + (lane & 15);
          int trow0 = rb * 16 + (lane >> 4) * 4;
#pragma unroll
          for (int reg = 0; reg < 4; ++reg)
            trb[(trow0 + reg) * 260 + tcol] = acc[rb][cb][reg];
        }
    }
    __syncthreads();
#pragma unroll
    for (int jj = 0; jj < 4; ++jj) {
      int rq = rw + jj * 8;
      int g = p * 32 + rq;
      long brow = b0 + g;
      float4 tv = *(float4*)&trb[rq * 260 + cg];
      float4 dv = fd[jj], xv = fx[jj];
      float p0 = dv.x / (1.f + __expf(-tv.x));
      float p1 = dv.y / (1.f + __expf(-tv.y));
      float p2 = dv.z / (1.f + __expf(-tv.z));
      float p3 = dv.w / (1.f + __expf(-tv.w));
      f32x4 outv = {p0, p1, p2, p3};
      __builtin_nontemporal_store(outv, (f32x4*)(mw + brow * 65536 + n0 + cg));
      int2 wb = make_int2(pkbf(p0 * xv.x, p1 * xv.y), pkbf(p2 * xv.z, p3 * xv.w));
      *(int2*)(wi + brow * 69632 + n0 + cg) = wb;
    }
  }
}

// ---- MFMA GEMM F1: wi(bf16) @ Wf1 -> f1part[64] (bf16) ----
// BM=256 BN=128 BK=64, split-K=64 -> grid 512 = 2 resident blocks/CU.
// A via global_load_lds (dbuf, pre-swizzled source); B single-buffered.
__global__ __launch_bounds__(512) void gemm_f1(
    const ushort* __restrict__ wi, const float* __restrict__ Wf1,
    ushort* __restrict__ f1part) {
  __shared__ char Asl[2][32768];  // 256 rows x 128B (64 bf16), XOR-swizzled
  __shared__ char Bsl[16384];     // 128 n    x 128B, XOR-swizzled (single)
  int bid = blockIdx.x;
  int L = (bid & 7) * 64 + (bid >> 3);  // XCD swizzle: same-kb tiles colocate
  int kb = L >> 3;                       // [0,64)
  int tile = L & 7;
  int mt = tile >> 2, nt = tile & 3;
  int b0 = mt * 256, n0 = nt * 128;
  int kc0 = kb * 1088;
  int t = threadIdx.x;
  int lane = t & 63, wid = t >> 6;
  int wr = wid >> 1, wc = wid & 1;  // 4x2 waves, wave tile 64x64

  f32x4 acc[4][4];
#pragma unroll
  for (int i = 0; i < 4; i++)
#pragma unroll
    for (int j = 0; j < 4; j++) acc[i][j] = f32x4{0.f, 0.f, 0.f, 0.f};

  int nn = t & 127, kg = (t >> 7) & 3;  // B loader roles
  float bvv[16];

  const char* wib = (const char*)wi;
  long arowbase = (long)(b0 + wid * 32 + (lane >> 3)) * 139264 +
                  (((lane & 7) ^ (lane >> 3)) << 4);

  auto STAGE_A = [&](int bi, int s) {
    const char* g0 = wib + arowbase + (long)(kc0 + s * 64) * 2;
    char* l0 = &Asl[bi][wid * 4096];
#pragma unroll
    for (int i = 0; i < 4; ++i)
      GLDS16(g0 + (long)i * 8 * 139264, l0 + i * 1024);
  };
  auto LOAD_B = [&](int s) {
    const float* bs = Wf1 + (long)(kc0 + s * 64 + kg * 16) * 512 + n0 + nn;
#pragma unroll
    for (int j = 0; j < 16; ++j) bvv[j] = bs[(long)j * 512];
  };
  auto WRITE_B = [&]() {
    unsigned p[8];
#pragma unroll
    for (int j = 0; j < 8; ++j) p[j] = pkbf(bvv[2 * j], bvv[2 * j + 1]);
    int o0 = nn * 128 + ((kg * 32) ^ ((nn & 7) << 4));
    int o1 = nn * 128 + ((kg * 32 + 16) ^ ((nn & 7) << 4));
    *(int4*)(Bsl + o0) = make_int4(p[0], p[1], p[2], p[3]);
    *(int4*)(Bsl + o1) = make_int4(p[4], p[5], p[6], p[7]);
  };

  STAGE_A(0, 0);
  LOAD_B(0);
  int cur = 0;
  for (int s = 0; s < 17; ++s) {
    __syncthreads();  // drains vmcnt: A(s) in LDS, bvv(s) in regs; Bsl free
    WRITE_B();
    if (s < 16) {
      STAGE_A(cur ^ 1, s + 1);  // issue next-step loads: in flight over MFMA
      LOAD_B(s + 1);
    }
    asm volatile("s_waitcnt lgkmcnt(0)" ::: "memory");  // my ds_writes done
    __builtin_amdgcn_s_barrier();                       // B visible; vmcnt live
    __builtin_amdgcn_sched_barrier(0);
    const char* Ab = &Asl[cur][0];
#pragma unroll
    for (int kk = 0; kk < 2; ++kk) {
      int kbyte = kk * 64 + (lane >> 4) * 16;
      short8 af[4], bfr[4];
#pragma unroll
      for (int rb = 0; rb < 4; ++rb) {
        int rr = wr * 64 + rb * 16 + (lane & 15);
        af[rb] = *(const short8*)(Ab + rr * 128 + (kbyte ^ ((rr & 7) << 4)));
      }
#pragma unroll
      for (int cb = 0; cb < 4; ++cb) {
        int nc = wc * 64 + cb * 16 + (lane & 15);
        bfr[cb] = *(const short8*)(Bsl + nc * 128 + (kbyte ^ ((nc & 7) << 4)));
      }
#pragma unroll
      for (int rb = 0; rb < 4; ++rb)
#pragma unroll
        for (int cb = 0; cb < 4; ++cb)
          acc[rb][cb] = __builtin_amdgcn_mfma_f32_16x16x32_bf16(af[rb], bfr[cb], acc[rb][cb], 0, 0, 0);
    }
    cur ^= 1;
  }
  ushort* P = f1part + (long)kb * 262144;
#pragma unroll
  for (int rb = 0; rb < 4; ++rb)
#pragma unroll
    for (int cb = 0; cb < 4; ++cb) {
      int nl = n0 + wc * 64 + cb * 16 + (lane & 15);
#pragma unroll
      for (int reg = 0; reg < 4; ++reg) {
        int bl = b0 + wr * 64 + rb * 16 + (lane >> 4) * 4 + reg;
        __hip_bfloat16 hb = __float2bfloat16(acc[rb][cb][reg]);
        P[bl * 512 + nl] = *reinterpret_cast<ushort*>(&hb);
      }
    }
}

// ------------- reduce f1part (64 x bf16) + LN + relu -------------
__global__ __launch_bounds__(512) void ln_f1(
    const ushort* __restrict__ f1part, const float* __restrict__ bf1,
    const float* __restrict__ gf1, const float* __restrict__ bef1,
    float* __restrict__ f1ln) {
  __shared__ float red[8];
  int b = blockIdx.x, t = threadIdx.x;
  float v = bf1[t];
#pragma unroll
  for (int s = 0; s < 64; ++s) v += bf2f(f1part[(long)s * 262144 + b * 512 + t]);
  float mu = block_sum<512>(v, red) * (1.f / 512.f);
  float d = v - mu;
  float var = block_sum<512>(d * d, red) * (1.f / 512.f);
  float y = d / sqrtf(var + 1e-5f) * gf1[t] + bef1[t];
  f1ln[b * 512 + t] = fmaxf(y, 0.f);
}

// ------------- f2 = relu(LN(f1ln @ Wf2 + bf2)) -------------
__global__ __launch_bounds__(256) void f2_head(
    const float* __restrict__ f1ln, const float* __restrict__ Wf2,
    const float* __restrict__ bf2, const float* __restrict__ gf2,
    const float* __restrict__ bef2, float* __restrict__ f2) {
  __shared__ float row[512];
  __shared__ float red[4];
  int b = blockIdx.x, t = threadIdx.x;
  row[t] = f1ln[b * 512 + t];
  row[t + 256] = f1ln[b * 512 + 256 + t];
  __syncthreads();
  float acc = bf2[t];
  for (int k = 0; k < 512; ++k) acc += row[k] * Wf2[k * 256 + t];
  float mu = block_sum<256>(acc, red) * (1.f / 256.f);
  float d = acc - mu;
  float var = block_sum<256>(d * d, red) * (1.f / 256.f);
  float y = d / sqrtf(var + 1e-5f) * gf2[t] + bef2[t];
  f2[b * 256 + t] = fmaxf(y, 0.f);
}

// ------------- logits -> softmax -> final -------------
__global__ __launch_bounds__(64) void final_head(
    const float* __restrict__ f2, const float* __restrict__ Wo,
    const float* __restrict__ bo, const float* __restrict__ est,
    float* __restrict__ fin) {
  __shared__ float row[256];
  int b = blockIdx.x, t = threadIdx.x;
#pragma unroll
  for (int i = 0; i < 4; ++i) row[t + i * 64] = f2[b * 256 + t + i * 64];
  __syncthreads();
  float lg = -1e30f;
  if (t < 16) {
    lg = bo[t];
    for (int k = 0; k < 256; ++k) lg += row[k] * Wo[k * 16 + t];
  }
  float m = lg;
#pragma unroll
  for (int o = 8; o > 0; o >>= 1) m = fmaxf(m, __shfl_xor(m, o, 64));
  float e = (t < 16) ? expf(lg - m) : 0.f;
  float ssum = e;
#pragma unroll
  for (int o = 8; o > 0; o >>= 1) ssum += __shfl_xor(ssum, o, 64);
  if (t < 16) fin[b * 16 + t] = 0.5f * (e / ssum + est[b * 16 + t]);
}

extern "C" void kernel_launch(void* const* d_in, const int* in_sizes, int n_in,
                              void* d_out, int out_size, void* d_ws, size_t ws_size,
                              hipStream_t stream) {
  const float* X = (const float*)d_in[0];
  const float* coverage = (const float*)d_in[1];
  const float* conc_grid = (const float*)d_in[2];
  const float* dist_table = (const float*)d_in[3];
  const float* W1 = (const float*)d_in[4];
  const float* b1 = (const float*)d_in[5];
  const float* g1 = (const float*)d_in[6];
  const float* be1 = (const float*)d_in[7];
  const float* W2 = (const float*)d_in[8];
  const float* b2 = (const float*)d_in[9];
  const float* g2 = (const float*)d_in[10];
  const float* be2 = (const float*)d_in[11];
  const float* W3 = (const float*)d_in[12];
  const float* b3 = (const float*)d_in[13];
  const float* Wm1 = (const float*)d_in[14];
  const float* bm1 = (const float*)d_in[15];
  const float* gm = (const float*)d_in[16];
  const float* bem = (const float*)d_in[17];
  const float* Wm2 = (const float*)d_in[18];
  const float* bm2 = (const float*)d_in[19];
  const float* Wf1 = (const float*)d_in[20];
  const float* bf1 = (const float*)d_in[21];
  const float* gf1 = (const float*)d_in[22];
  const float* bef1 = (const float*)d_in[23];
  const float* Wf2 = (const float*)d_in[24];
  const float* bf2 = (const float*)d_in[25];
  const float* gf2 = (const float*)d_in[26];
  const float* bef2 = (const float*)d_in[27];
  const float* Wo = (const float*)d_in[28];
  const float* bo = (const float*)d_in[29];

  float* out_final = (float*)d_out;
  float* out_est = out_final + 8192;
  float* out_mw = out_final + 16384;

  char* ws = (char*)d_ws;
  float* ci = (float*)(ws);                       // 16.78 MB
  float* part = (float*)(ws + 16777216);          // 33.5 MB (gemm1 partials)
  ushort* f1part = (ushort*)(ws + 16777216);      // 33.5 MB (aliases part; after gemm_m2)
  float* h1 = (float*)(ws + 50331648);            // 512 KB
  ushort* lh = (ushort*)(ws + 50855936);          // 256 KB bf16
  int* idxb = (int*)(ws + 51118080);              // 32 KB
  float* f1ln = (float*)(ws + 51150848);          // 1 MB
  float* f2 = (float*)(ws + 52199424);            // 512 KB
  ushort* wi = (ushort*)(ws + 52723712);          // 71.3 MB bf16 [512][69632]
  ushort* Wm2T = (ushort*)(ws + 124780544);       // 33.5 MB (separate: coexists with part)

  prep_ci<<<2048, 256, 0, stream>>>(X, coverage, ci, wi);
  gemm1_cast<<<1536, 256, 0, stream>>>(ci, W1, Wm1, part, Wm2, Wm2T);
  ln_dual<<<1024, 256, 0, stream>>>(part, b1, g1, be1, bm1, gm, bem, h1, lh);
  est_head<<<512, 64, 0, stream>>>(h1, W2, b2, g2, be2, W3, b3, conc_grid, out_est, idxb);
  gemm_m2<<<2048, 512, 0, stream>>>(lh, Wm2T, bm2, idxb, dist_table, ci, out_mw, wi);
  gemm_f1<<<512, 512, 0, stream>>>(wi, Wf1, f1part);
  ln_f1<<<512, 512, 0, stream>>>(f1part, bf1, gf1, bef1, f1ln);
  f2_head<<<512, 256, 0, stream>>>(f1ln, Wf2, bf2, gf2, bef2, f2);
  final_head<<<512, 64, 0, stream>>>(f2, Wo, bo, out_est, out_final);
}